// Round 11
// baseline (86.527 us; speedup 1.0000x reference)
//
#include <hip/hip_runtime.h>

#define A_ 8732
#define B_ 32
#define N_ 100
#define ABLK 35            // ceil(A_/256)
#define GB_G 8             // GTs per group in k_scan
#define G0 4               // launched group-stride (typical G: ceil(~25/8)=4)
#define SPLIT 16           // anchor-axis splits
#define SLEN 546           // ceil(A_/SPLIT); last split = 542 (>=256)
#define EPSF 1e-6f

// ws layout: wsplit[B_*SPLIT*N_] u64 only (410 KB; valid-n slots only).
// The per-anchor direction is recomputed in k_finalize from LDS-staged GTs
// (~25 IoUs/anchor) instead of materializing 9 MB of per-anchor key planes.

// Deterministic in-block compaction of valid GTs (x1>x0 && y1>y0), rank =
// ascending original n — identical in every block of a batch (required for
// split/group coverage). Inverted GTs have IoU == +0 vs EVERY anchor
// (rx <= x1 < x0 <= lx => w=0) and are covered exactly by zero-key inits.

// ---------------------------------------------------------------------------
// K1: per-GT direction ONLY. Block (b, g0, s) handles groups g = g0, g0+G0,
// ... (8g < c) over anchors [s*SLEN, min(A_,(s+1)*SLEN)).
// Per-GT key (iou<<32)|(inv a); per-lane init (0, inv(first lane anchor));
// in-wave shfl_xor max + cross-wave LDS merge -> wsplit[b][s][n]. Cross-split
// max in finalize keeps global first-occurrence (inv strictly decreasing).
// IoU expressions verbatim from the R6..R10-passing kernels.
// ---------------------------------------------------------------------------
__global__ __launch_bounds__(256) void k_scan(
    const float* __restrict__ gt, const float* __restrict__ anchors,
    unsigned long long* __restrict__ wsplit) {
  int tid = threadIdx.x;
  int lane = tid & 63, wid = tid >> 6;
  int bid = blockIdx.x;
  int s = bid % SPLIT;
  int t = bid / SPLIT;
  int g0 = t % G0;
  int b = t / G0;

  __shared__ unsigned long long s_bal[2];
  __shared__ int s_slot[N_];
  __shared__ unsigned long long s_w[4][GB_G];

  // ---- deterministic compaction ----
  bool v = false;
  if (tid < N_) {
    float4 myg = ((const float4*)gt)[b * N_ + tid];
    v = (myg.z > myg.x && myg.w > myg.y);
  }
  unsigned long long bal = __ballot(v);
  if (lane == 0 && wid < 2) s_bal[wid] = bal;
  __syncthreads();
  int c0 = __popcll(s_bal[0]);
  int c = c0 + __popcll(s_bal[1]);  // waves 2,3: tid>=128 -> v=false
  if (v) {
    int rank = __popcll(bal & ((1ull << lane) - 1)) + (wid ? c0 : 0);
    s_slot[rank] = tid;
  }
  __syncthreads();

  int s0 = s * SLEN;
  int send = (s0 + SLEN < A_) ? (s0 + SLEN) : A_;

  for (int g = g0; GB_G * g < c; g += G0) {  // uniform condition
    float gx0[GB_G], gy0[GB_G], gx1[GB_G], gy1[GB_G], gar[GB_G];
    bool live[GB_G];
#pragma unroll
    for (int j = 0; j < GB_G; j++) {
      int p = GB_G * g + j;
      live[j] = p < c;
      int nj = live[j] ? s_slot[p] : 0;
      float4 gb = ((const float4*)gt)[b * N_ + nj];
      if (!live[j]) gb = make_float4(1.0f, 1.0f, 0.0f, 0.0f);  // inverted
      gx0[j] = gb.x; gy0[j] = gb.y; gx1[j] = gb.z; gy1[j] = gb.w;
      gar[j] = (gb.z - gb.x) * (gb.w - gb.y);
    }
    unsigned long long wkey[GB_G];
#pragma unroll
    for (int j = 0; j < GB_G; j++)
      wkey[j] = (unsigned long long)(0xFFFFFFFFu - (unsigned)(s0 + tid));

    for (int a = s0 + tid; a < send; a += 256) {
      float4 an = ((const float4*)anchors)[a];
      float ax0 = an.x - an.z * 0.5f, ay0 = an.y - an.w * 0.5f;
      float ax1 = an.x + an.z * 0.5f, ay1 = an.y + an.w * 0.5f;
      float area_a = (ax1 - ax0) * (ay1 - ay0);
#pragma unroll
      for (int j = 0; j < GB_G; j++) {
        float lx = fmaxf(ax0, gx0[j]), ly = fmaxf(ay0, gy0[j]);
        float rx = fminf(ax1, gx1[j]), ry = fminf(ay1, gy1[j]);
        float w = fmaxf(rx - lx, 0.0f), h = fmaxf(ry - ly, 0.0f);
        float inter = w * h;
        if (inter > 0.0f) {  // exact skip: zero-iou covered by inits
          float uni = area_a + gar[j] - inter;
          float iou = inter / fmaxf(uni, EPSF);
          unsigned long long kB =
              (((unsigned long long)__float_as_uint(iou)) << 32) |
              (unsigned long long)(0xFFFFFFFFu - (unsigned)a);
          if (kB > wkey[j]) wkey[j] = kB;
        }
      }
    }

    // ---- per-GT reduction: in-wave shfl_xor max, then cross-wave merge ----
#pragma unroll
    for (int j = 0; j < GB_G; j++) {
      unsigned long long k = wkey[j];
#pragma unroll
      for (int off = 32; off; off >>= 1) {
        unsigned long long o = __shfl_xor(k, off, 64);
        if (o > k) k = o;
      }
      if (lane == 0) s_w[wid][j] = k;
    }
    __syncthreads();
    if (tid < GB_G) {
      int j = tid;
      if (GB_G * g + j < c) {
        unsigned long long k = s_w[0][j];
#pragma unroll
        for (int w2 = 1; w2 < 4; w2++)
          if (s_w[w2][j] > k) k = s_w[w2][j];
        wsplit[((size_t)b * SPLIT + s) * N_ + s_slot[GB_G * g + j]] = k;
      }
    }
    __syncthreads();
  }
}

// ---------------------------------------------------------------------------
// K2: per (b, 256-anchor tile). Ballot-compacts + LDS-stages the valid GTs
// (same deterministic predicate/rank), then:
//  - per-n winner: inverted GT -> aw=0 (numpy zero-column argmax); valid ->
//    max over 16 split keys. Override via LDS atomicMax over n (last-write-
//    wins index_put).
//  - per-anchor argmax recomputed in-block: init key (0,99) (decodes gi=0;
//    dominates all zero-iou candidates exactly), loop c staged GTs with the
//    verbatim IoU + exact inter>0 skip, key (iou<<32)|(99-n).
// Encode expressions verbatim.
// ---------------------------------------------------------------------------
__global__ __launch_bounds__(256) void k_finalize(
    const float* __restrict__ gt, const int* __restrict__ labels,
    const float* __restrict__ anchors, const unsigned char* __restrict__ mask,
    const unsigned long long* __restrict__ wsplit, float* __restrict__ out) {
  int b = blockIdx.y;
  int a0 = blockIdx.x * 256;
  int tid = threadIdx.x;
  int lane = tid & 63, wid = tid >> 6;
  int a = a0 + tid;

  __shared__ int s_ov[256];
  __shared__ int s_any;
  __shared__ unsigned long long s_bal[2];
  __shared__ float s_bx0[N_], s_by0[N_], s_bx1[N_], s_by1[N_], s_ar[N_];
  __shared__ unsigned s_inv[N_];  // 99 - n

  bool v = false;
  float4 myg;
  if (tid < N_) {
    myg = ((const float4*)gt)[b * N_ + tid];
    v = (myg.z > myg.x && myg.w > myg.y);
  }
  unsigned long long bal = __ballot(v);
  if (lane == 0 && wid < 2) s_bal[wid] = bal;
  if (tid == 0) s_any = 0;
  s_ov[tid] = -1;
  __syncthreads();
  int c0 = __popcll(s_bal[0]);
  int c = c0 + __popcll(s_bal[1]);
  if (v) {
    int rank = __popcll(bal & ((1ull << lane) - 1)) + (wid ? c0 : 0);
    s_bx0[rank] = myg.x; s_by0[rank] = myg.y;
    s_bx1[rank] = myg.z; s_by1[rank] = myg.w;
    s_ar[rank] = (myg.z - myg.x) * (myg.w - myg.y);  // verbatim expr
    s_inv[rank] = (unsigned)(N_ - 1 - tid);
  }

  if (tid < N_) {
    int aw = 0;  // inverted GT: all-zero column -> argmax anchor 0
    if (v) {
      const unsigned long long* wp = wsplit + (size_t)b * SPLIT * N_ + tid;
      unsigned long long k = wp[0];
#pragma unroll
      for (int s2 = 1; s2 < SPLIT; s2++) {
        unsigned long long tk = wp[(size_t)s2 * N_];
        if (tk > k) k = tk;
      }
      aw = (int)(0xFFFFFFFFu - (unsigned)(k & 0xFFFFFFFFull));
    }
    if (aw >= a0 && aw < a0 + 256) atomicMax(&s_ov[aw - a0], tid);
  }
  if (tid < 25) {
    unsigned mv = ((const unsigned*)mask)[b * 25 + tid];
    if (mv) atomicOr(&s_any, 1);
  }
  __syncthreads();
  if (a >= A_) return;

  // ---- per-anchor argmax over the c staged GTs (verbatim math + skip) ----
  float4 an = ((const float4*)anchors)[a];
  float ax0 = an.x - an.z * 0.5f, ay0 = an.y - an.w * 0.5f;
  float ax1 = an.x + an.z * 0.5f, ay1 = an.y + an.w * 0.5f;
  float area_a = (ax1 - ax0) * (ay1 - ay0);

  unsigned long long k = (unsigned long long)(unsigned)(N_ - 1);  // (0, n=0)
  for (int j = 0; j < c; j++) {
    float lx = fmaxf(ax0, s_bx0[j]), ly = fmaxf(ay0, s_by0[j]);
    float rx = fminf(ax1, s_bx1[j]), ry = fminf(ay1, s_by1[j]);
    float w = fmaxf(rx - lx, 0.0f), h = fmaxf(ry - ly, 0.0f);
    float inter = w * h;
    if (inter > 0.0f) {  // exact skip: zero-iou covered by init (0,99)
      float uni = area_a + s_ar[j] - inter;
      float iou = inter / fmaxf(uni, EPSF);
      unsigned long long kc =
          (((unsigned long long)__float_as_uint(iou)) << 32) |
          (unsigned long long)s_inv[j];
      if (kc > k) k = kc;
    }
  }
  float iou = __uint_as_float((unsigned)(k >> 32));
  int gi = (N_ - 1) - (int)(k & 0xFFFFFFFFull);

  int ov = s_ov[tid];
  bool pos;
  if (ov >= 0) {
    gi = ov;
    pos = true;  // scattered best_gt_iou = 2.0 > 0.5
  } else {
    pos = iou > 0.5f;
  }

  const float* g = gt + (size_t)(b * N_ + gi) * 4;
  float gx = g[0], gy = g[1], gw = g[2], gh = g[3];

  float ex = (gx - an.x) / an.z;
  float ey = (gy - an.y) / an.w;
  float ew = logf((gw + EPSF) / (an.z + EPSF));
  float eh = logf((gh + EPSF) / (an.w + EPSF));
  int lab = pos ? labels[b * N_ + gi] : 0;

  if (!s_any) { ex = 0.0f; ey = 0.0f; ew = 0.0f; eh = 0.0f; lab = 0; }

  const long long BA = (long long)B_ * A_;
  ((float4*)out)[(size_t)b * A_ + a] = make_float4(ex, ey, ew, eh);
  out[4 * BA + (size_t)b * A_ + a] = (float)lab;
  out[5 * BA + (size_t)b * A_ + a] = pos ? 1.0f : 0.0f;
}

extern "C" void kernel_launch(void* const* d_in, const int* in_sizes, int n_in,
                              void* d_out, int out_size, void* d_ws,
                              size_t ws_size, hipStream_t stream) {
  const float* gt = (const float*)d_in[0];
  const int* labels = (const int*)d_in[1];
  const unsigned char* mask = (const unsigned char*)d_in[2];
  const float* anchors = (const float*)d_in[3];
  float* out = (float*)d_out;

  unsigned long long* wsplit = (unsigned long long*)d_ws;  // B*SPLIT*N u64

  k_scan<<<B_ * G0 * SPLIT, 256, 0, stream>>>(gt, anchors, wsplit);
  k_finalize<<<dim3(ABLK, B_), 256, 0, stream>>>(gt, labels, anchors, mask,
                                                 wsplit, out);
}

// Round 12
// 82.063 us; speedup vs baseline: 1.0544x; 1.0544x over previous
//
#include <hip/hip_runtime.h>

#define A_ 8732
#define B_ 32
#define N_ 100
#define ABLK 35            // ceil(A_/256)
#define GB_G 4             // GTs per scan block
#define GMAX 25            // max groups per batch (N_/GB_G)
#define SPLIT 8            // anchor-axis splits per group
#define SLEN 1092          // ceil(A_/SPLIT); last split = 1088 (>=256)
#define EPSF 1e-6f

// ws layout (only regions written this launch are later read):
//   partial[B_*GMAX*A_] u64 (only planes g<ceil(c/4) written+read)
//   wsplit[B_*SPLIT*N_] u64 (only valid-n slots written+read)

// Deterministic in-block compaction of valid GTs (x1>x0 && y1>y0), rank =
// ascending original n — identical in every block of a batch, which the
// split-coverage argument requires. Inverted GTs have IoU == +0 vs EVERY
// anchor (rx <= x1 < x0 <= lx => w=0) and are handled exactly by the
// zero-key inits downstream.

// ---------------------------------------------------------------------------
// K1: block (b, g, s) scans anchors [s*SLEN, min(A_,(s+1)*SLEN)) for the 4
// GTs of compacted group g; BOTH directions in one pass:
//  - per-anchor partial key (iou<<32)|(99-n) -> prow[a] (one writer per a).
//  - per-GT key (iou<<32)|(inv a); per-lane init (0, inv(first lane anchor));
//    in-wave shfl_xor max (6 rounds, no barriers) + 4-entry cross-wave LDS
//    merge -> wsplit[b][s][n]. Cross-split max in finalize keeps global
//    first-occurrence (inv strictly decreasing in a).
// ---------------------------------------------------------------------------
__global__ __launch_bounds__(256) void k_scan(
    const float* __restrict__ gt, const float* __restrict__ anchors,
    unsigned long long* __restrict__ partial,
    unsigned long long* __restrict__ wsplit) {
  int tid = threadIdx.x;
  int lane = tid & 63, wid = tid >> 6;
  int bid = blockIdx.x;
  int s = bid % SPLIT;
  int t = bid / SPLIT;
  int g = t % GMAX;
  int b = t / GMAX;

  __shared__ unsigned long long s_bal[2];
  __shared__ int s_slot[N_];
  __shared__ unsigned long long s_w[4][GB_G];

  // ---- deterministic compaction ----
  bool v = false;
  float4 myg;
  if (tid < N_) {
    myg = ((const float4*)gt)[b * N_ + tid];
    v = (myg.z > myg.x && myg.w > myg.y);
  }
  unsigned long long bal = __ballot(v);
  if (lane == 0 && wid < 2) s_bal[wid] = bal;
  __syncthreads();
  int c0 = __popcll(s_bal[0]);
  int c = c0 + __popcll(s_bal[1]);  // waves 2,3: tid>=128 -> v=false
  if (v) {
    int rank = __popcll(bal & ((1ull << lane) - 1)) + (wid ? c0 : 0);
    s_slot[rank] = tid;
  }
  __syncthreads();
  if (GB_G * g >= c) return;

  // ---- load this group's 4 GTs (area expr verbatim) ----
  float gx0[GB_G], gy0[GB_G], gx1[GB_G], gy1[GB_G], gar[GB_G];
  int gn[GB_G];
  bool live[GB_G];
#pragma unroll
  for (int j = 0; j < GB_G; j++) {
    int p = GB_G * g + j;
    live[j] = p < c;
    int nj = live[j] ? s_slot[p] : 0;
    gn[j] = nj;
    float4 gb = ((const float4*)gt)[b * N_ + nj];
    if (!live[j]) gb = make_float4(1.0f, 1.0f, 0.0f, 0.0f);  // inverted dummy
    gx0[j] = gb.x; gy0[j] = gb.y; gx1[j] = gb.z; gy1[j] = gb.w;
    gar[j] = (gb.z - gb.x) * (gb.w - gb.y);
  }

  int s0 = s * SLEN;
  int send = (s0 + SLEN < A_) ? (s0 + SLEN) : A_;

  unsigned long long wkey[GB_G];
#pragma unroll
  for (int j = 0; j < GB_G; j++)
    wkey[j] = (unsigned long long)(0xFFFFFFFFu - (unsigned)(s0 + tid));

  unsigned long long* prow = partial + ((size_t)b * GMAX + g) * A_;
  for (int a = s0 + tid; a < send; a += 256) {
    float4 an = ((const float4*)anchors)[a];
    float ax0 = an.x - an.z * 0.5f, ay0 = an.y - an.w * 0.5f;
    float ax1 = an.x + an.z * 0.5f, ay1 = an.y + an.w * 0.5f;
    float area_a = (ax1 - ax0) * (ay1 - ay0);
    unsigned long long pk = 0ull;
#pragma unroll
    for (int j = 0; j < GB_G; j++) {
      float lx = fmaxf(ax0, gx0[j]), ly = fmaxf(ay0, gy0[j]);
      float rx = fminf(ax1, gx1[j]), ry = fminf(ay1, gy1[j]);
      float w = fmaxf(rx - lx, 0.0f), h = fmaxf(ry - ly, 0.0f);
      float inter = w * h;
      if (inter > 0.0f) {  // exact skip: zero-iou covered by inits
        float uni = area_a + gar[j] - inter;
        float iou = inter / fmaxf(uni, EPSF);
        unsigned long long hi = ((unsigned long long)__float_as_uint(iou)) << 32;
        unsigned long long kA = hi | (unsigned long long)(unsigned)(N_ - 1 - gn[j]);
        if (kA > pk) pk = kA;
        unsigned long long kB = hi | (unsigned long long)(0xFFFFFFFFu - (unsigned)a);
        if (kB > wkey[j]) wkey[j] = kB;
      }
    }
    prow[a] = pk;
  }

  // ---- per-GT reduction: in-wave shfl_xor max, then cross-wave merge ----
#pragma unroll
  for (int j = 0; j < GB_G; j++) {
    unsigned long long k = wkey[j];
#pragma unroll
    for (int off = 32; off; off >>= 1) {
      unsigned long long o = __shfl_xor(k, off, 64);
      if (o > k) k = o;
    }
    if (lane == 0) s_w[wid][j] = k;
  }
  __syncthreads();
  if (tid < GB_G) {
    int j = tid;
    if (GB_G * g + j < c) {
      unsigned long long k = s_w[0][j];
#pragma unroll
      for (int w2 = 1; w2 < 4; w2++)
        if (s_w[w2][j] > k) k = s_w[w2][j];
      wsplit[((size_t)b * SPLIT + s) * N_ + s_slot[GB_G * g + j]] = k;
    }
  }
}

// ---------------------------------------------------------------------------
// K2: per (b, 256-anchor tile) — c recomputed by the same deterministic
// ballot (G = ceil(c/4) bounds the plane merge). Per-n winner: inverted GT
// -> aw=0 (numpy zero-column argmax); valid -> max over 8 split keys.
// Override via LDS atomicMax over n (= last-write-wins index_put).
// Per-anchor merge from init (0,99) (decodes gi=0; dominates all zero-iou
// candidates and 0ull partials). Encode expressions verbatim.
// ---------------------------------------------------------------------------
__global__ __launch_bounds__(256) void k_finalize(
    const float* __restrict__ gt, const int* __restrict__ labels,
    const float* __restrict__ anchors, const unsigned char* __restrict__ mask,
    const unsigned long long* __restrict__ partial,
    const unsigned long long* __restrict__ wsplit, float* __restrict__ out) {
  int b = blockIdx.y;
  int a0 = blockIdx.x * 256;
  int tid = threadIdx.x;
  int lane = tid & 63, wid = tid >> 6;
  int a = a0 + tid;

  __shared__ int s_ov[256];
  __shared__ int s_any;
  __shared__ unsigned long long s_bal[2];

  bool v = false;
  if (tid < N_) {
    float4 gb = ((const float4*)gt)[b * N_ + tid];
    v = (gb.z > gb.x && gb.w > gb.y);
  }
  unsigned long long bal = __ballot(v);
  if (lane == 0 && wid < 2) s_bal[wid] = bal;
  if (tid == 0) s_any = 0;
  s_ov[tid] = -1;
  __syncthreads();
  int c = __popcll(s_bal[0]) + __popcll(s_bal[1]);

  if (tid < N_) {
    int aw = 0;  // inverted GT: all-zero column -> argmax anchor 0
    if (v) {
      const unsigned long long* wp = wsplit + (size_t)b * SPLIT * N_ + tid;
      unsigned long long k = wp[0];
#pragma unroll
      for (int s2 = 1; s2 < SPLIT; s2++) {
        unsigned long long tk = wp[(size_t)s2 * N_];
        if (tk > k) k = tk;
      }
      aw = (int)(0xFFFFFFFFu - (unsigned)(k & 0xFFFFFFFFull));
    }
    if (aw >= a0 && aw < a0 + 256) atomicMax(&s_ov[aw - a0], tid);
  }
  if (tid < 25) {
    unsigned mv = ((const unsigned*)mask)[b * 25 + tid];
    if (mv) atomicOr(&s_any, 1);
  }
  __syncthreads();
  if (a >= A_) return;

  int G = (c + GB_G - 1) / GB_G;  // block-uniform
  unsigned long long k = (unsigned long long)(unsigned)(N_ - 1);  // (0, n=0)
  const unsigned long long* prow = partial + (size_t)b * GMAX * A_ + a;
  for (int g2 = 0; g2 < G; g2++) {
    unsigned long long t2 = prow[(size_t)g2 * A_];
    if (t2 > k) k = t2;
  }
  float iou = __uint_as_float((unsigned)(k >> 32));
  int gi = (N_ - 1) - (int)(k & 0xFFFFFFFFull);

  int ov = s_ov[tid];
  bool pos;
  if (ov >= 0) {
    gi = ov;
    pos = true;  // scattered best_gt_iou = 2.0 > 0.5
  } else {
    pos = iou > 0.5f;
  }

  float4 an = ((const float4*)anchors)[a];
  const float* g = gt + (size_t)(b * N_ + gi) * 4;
  float gx = g[0], gy = g[1], gw = g[2], gh = g[3];

  float ex = (gx - an.x) / an.z;
  float ey = (gy - an.y) / an.w;
  float ew = logf((gw + EPSF) / (an.z + EPSF));
  float eh = logf((gh + EPSF) / (an.w + EPSF));
  int lab = pos ? labels[b * N_ + gi] : 0;

  if (!s_any) { ex = 0.0f; ey = 0.0f; ew = 0.0f; eh = 0.0f; lab = 0; }

  const long long BA = (long long)B_ * A_;
  ((float4*)out)[(size_t)b * A_ + a] = make_float4(ex, ey, ew, eh);
  out[4 * BA + (size_t)b * A_ + a] = (float)lab;
  out[5 * BA + (size_t)b * A_ + a] = pos ? 1.0f : 0.0f;
}

extern "C" void kernel_launch(void* const* d_in, const int* in_sizes, int n_in,
                              void* d_out, int out_size, void* d_ws,
                              size_t ws_size, hipStream_t stream) {
  const float* gt = (const float*)d_in[0];
  const int* labels = (const int*)d_in[1];
  const unsigned char* mask = (const unsigned char*)d_in[2];
  const float* anchors = (const float*)d_in[3];
  float* out = (float*)d_out;

  unsigned long long* partial = (unsigned long long*)d_ws;        // B*GMAX*A
  unsigned long long* wsplit = partial + (size_t)B_ * GMAX * A_;  // B*SPLIT*N

  k_scan<<<B_ * GMAX * SPLIT, 256, 0, stream>>>(gt, anchors, partial, wsplit);
  k_finalize<<<dim3(ABLK, B_), 256, 0, stream>>>(gt, labels, anchors, mask,
                                                 partial, wsplit, out);
}